// Round 3
// baseline (1436.440 us; speedup 1.0000x reference)
//
#include <hip/hip_runtime.h>
#include <hip/hip_cooperative_groups.h>

namespace cg = cooperative_groups;

#define B_ 32
#define N_ 4096
#define D_ 512
#define S_ 8
#define ITERS_ 3
#define GRID_ 256
#define TPB_ 512

struct Params {
    const float *inputs, *noise, *mu, *sg;
    const float *ln_in_g, *ln_in_b, *ln_s_g, *ln_s_b;
    const float *wq, *wk, *wv, *w_ih, *w_hh, *b_ih, *b_hh;
    const float *ln_m_g, *ln_m_b, *w1, *b1, *w2, *b2;
    float *slots, *sn, *qk, *u0, *s2b, *h0, *hb, *gi, *gh, *Mqk, *Wiv, *part;
    float *out;
};

__device__ __forceinline__ float sigmoid_f(float x) {
    return 1.0f / (1.0f + __expf(-x));
}
__device__ __forceinline__ float tanh_f(float x) {
    float e = __expf(2.0f * x);          // inf-safe
    return 1.0f - 2.0f / (e + 1.0f);
}

// block-wide LN stats over 512 values (one per thread). red = 16-float LDS scratch.
__device__ __forceinline__ void row_stats(float val, float* red, int tid,
                                          float& mean, float& rs) {
    int wid = tid >> 6, lane = tid & 63;
    float s1 = val, s2 = val * val;
#pragma unroll
    for (int off = 32; off > 0; off >>= 1) {
        s1 += __shfl_xor(s1, off, 64);
        s2 += __shfl_xor(s2, off, 64);
    }
    if (lane == 0) { red[wid] = s1; red[8 + wid] = s2; }
    __syncthreads();
    float t1 = 0.f, t2 = 0.f;
#pragma unroll
    for (int i = 0; i < 8; ++i) { t1 += red[i]; t2 += red[8 + i]; }
    mean = t1 * (1.0f / D_);
    rs = rsqrtf(t2 * (1.0f / D_) - mean * mean + 1e-5f);
    __syncthreads();
}

// ---- 64x64 output tile GEMM, K=512 fixed, 512 threads, micro 4x2 ----
// AMODE 0: A row-major [M][512]; AMODE 1: A k-major [512][M'] (ld 512)
// WMODE 0: W row-major [N][512] (C = A @ W^T); WMODE 1: W k-major [512][N]
template<int AMODE, int WMODE, int RELU, int RESID>
__device__ void tile_mm(const float* __restrict__ A, const float* __restrict__ W,
                        const float* __restrict__ bias, const float* __restrict__ resid,
                        float* __restrict__ C, int ldc, int bm, int bn,
                        float* smem, int tid) {
    float (*As)[68] = (float (*)[68])smem;
    float (*Ws)[68] = (float (*)[68])(smem + 64 * 68);
    const int tm = tid >> 5, tn = tid & 31;
    float acc[4][2] = {{0.f,0.f},{0.f,0.f},{0.f,0.f},{0.f,0.f}};

    for (int kk = 0; kk < 512; kk += 64) {
        __syncthreads();
        if (AMODE == 0) {
#pragma unroll
            for (int r = 0; r < 2; ++r) {
                int flat = tid * 4 + r * 2048;
                int m = flat >> 6, k = flat & 63;
                float4 v = *(const float4*)(A + (size_t)(bm + m) * 512 + kk + k);
                As[k + 0][m] = v.x; As[k + 1][m] = v.y;
                As[k + 2][m] = v.z; As[k + 3][m] = v.w;
            }
        } else {
#pragma unroll
            for (int r = 0; r < 2; ++r) {
                int idx = tid + r * 512;
                int k = idx >> 4, m4 = idx & 15;
                *(float4*)&As[k][m4 << 2] =
                    *(const float4*)(A + (size_t)(kk + k) * 512 + bm + (m4 << 2));
            }
        }
        if (WMODE == 0) {
#pragma unroll
            for (int r = 0; r < 2; ++r) {
                int flat = tid * 4 + r * 2048;
                int n = flat >> 6, k = flat & 63;
                float4 v = *(const float4*)(W + (size_t)(bn + n) * 512 + kk + k);
                Ws[k + 0][n] = v.x; Ws[k + 1][n] = v.y;
                Ws[k + 2][n] = v.z; Ws[k + 3][n] = v.w;
            }
        } else {
#pragma unroll
            for (int r = 0; r < 2; ++r) {
                int idx = tid + r * 512;
                int k = idx >> 4, n4 = idx & 15;
                *(float4*)&Ws[k][n4 << 2] =
                    *(const float4*)(W + (size_t)(kk + k) * 512 + bn + (n4 << 2));
            }
        }
        __syncthreads();
#pragma unroll
        for (int k = 0; k < 64; ++k) {
            const float4 a = *(const float4*)&As[k][tm << 2];
            const float2 w = *(const float2*)&Ws[k][tn << 1];
            acc[0][0] = fmaf(a.x, w.x, acc[0][0]); acc[0][1] = fmaf(a.x, w.y, acc[0][1]);
            acc[1][0] = fmaf(a.y, w.x, acc[1][0]); acc[1][1] = fmaf(a.y, w.y, acc[1][1]);
            acc[2][0] = fmaf(a.z, w.x, acc[2][0]); acc[2][1] = fmaf(a.z, w.y, acc[2][1]);
            acc[3][0] = fmaf(a.w, w.x, acc[3][0]); acc[3][1] = fmaf(a.w, w.y, acc[3][1]);
        }
    }
    __syncthreads();
#pragma unroll
    for (int i = 0; i < 4; ++i) {
        int row = bm + (tm << 2) + i;
#pragma unroll
        for (int j = 0; j < 2; ++j) {
            int col = bn + (tn << 1) + j;
            float v = acc[i][j];
            if (bias)  v += bias[col];
            if (RELU)  v = fmaxf(v, 0.0f);
            if (RESID) v += resid[(size_t)row * ldc + col];
            C[(size_t)row * ldc + col] = v;
        }
    }
}

// ---- fused attention stage: LN(inputs) -> 8 logits -> softmax -> u0 partial ----
__device__ void attn_stage(const Params& p, int beta, int tid, float* smem) {
    float* qks = smem;           // 4096 floats
    float* u0s = smem + 4096;    // 4096 floats
    const int b = beta >> 3, c = beta & 7;
    const int wid = tid >> 6, lane = tid & 63;
    {
        const float4* src = (const float4*)(p.qk + (size_t)b * (S_ * D_));
        float4* dst = (float4*)qks;
        dst[tid] = src[tid];
        dst[tid + 512] = src[tid + 512];
    }
    __syncthreads();
    const float4* g4 = (const float4*)p.ln_in_g;
    const float4* b4 = (const float4*)p.ln_in_b;
    float4 glo = g4[lane], ghi = g4[64 + lane];
    float4 blo = b4[lane], bhi = b4[64 + lane];

    float4 alo[8], ahi[8];
#pragma unroll
    for (int s = 0; s < 8; ++s) {
        alo[s] = make_float4(0.f, 0.f, 0.f, 0.f);
        ahi[s] = make_float4(0.f, 0.f, 0.f, 0.f);
    }
    const float cnorm = 1.0f / (1.0f + 8.0f * 1e-8f);
    const float eadd  = 1e-8f * cnorm;
    const bool hb5 = (lane & 32) != 0, hb4 = (lane & 16) != 0, hb3 = (lane & 8) != 0;
    const int gbase = lane & 7;

    const float* xbase = p.inputs + ((size_t)b * N_ + (size_t)c * 512 + wid) * D_;
    float4 x0lo = ((const float4*)xbase)[lane];
    float4 x0hi = ((const float4*)xbase)[64 + lane];
    const float* x1p = xbase + 8 * D_;
    float4 x1lo = ((const float4*)x1p)[lane];
    float4 x1hi = ((const float4*)x1p)[64 + lane];

    for (int j = 0; j < 64; ++j) {
        int jn = (j < 62) ? j + 2 : 63;
        const float* xn = xbase + (size_t)jn * 8 * D_;
        float4 nlo = ((const float4*)xn)[lane];
        float4 nhi = ((const float4*)xn)[64 + lane];

        // LN stats
        float s1 = x0lo.x + x0lo.y + x0lo.z + x0lo.w + x0hi.x + x0hi.y + x0hi.z + x0hi.w;
        float s2 = x0lo.x*x0lo.x; s2 = fmaf(x0lo.y,x0lo.y,s2); s2 = fmaf(x0lo.z,x0lo.z,s2); s2 = fmaf(x0lo.w,x0lo.w,s2);
        s2 = fmaf(x0hi.x,x0hi.x,s2); s2 = fmaf(x0hi.y,x0hi.y,s2); s2 = fmaf(x0hi.z,x0hi.z,s2); s2 = fmaf(x0hi.w,x0hi.w,s2);
#pragma unroll
        for (int off = 32; off > 0; off >>= 1) {
            s1 += __shfl_xor(s1, off, 64);
            s2 += __shfl_xor(s2, off, 64);
        }
        float mean = s1 * (1.0f / D_);
        float var  = s2 * (1.0f / D_) - mean * mean;
        float rs   = rsqrtf(var + 1e-5f);
        float4 hlo, hhi;
        hlo.x = fmaf((x0lo.x - mean) * rs, glo.x, blo.x);
        hlo.y = fmaf((x0lo.y - mean) * rs, glo.y, blo.y);
        hlo.z = fmaf((x0lo.z - mean) * rs, glo.z, blo.z);
        hlo.w = fmaf((x0lo.w - mean) * rs, glo.w, blo.w);
        hhi.x = fmaf((x0hi.x - mean) * rs, ghi.x, bhi.x);
        hhi.y = fmaf((x0hi.y - mean) * rs, ghi.y, bhi.y);
        hhi.z = fmaf((x0hi.z - mean) * rs, ghi.z, bhi.z);
        hhi.w = fmaf((x0hi.w - mean) * rs, ghi.w, bhi.w);

        // per-lane partial logits (qk from LDS, contiguous b128 reads)
        float dd[8];
#pragma unroll
        for (int s = 0; s < 8; ++s) {
            const float4 ql = *(const float4*)&qks[s * 512 + (lane << 2)];
            const float4 qh = *(const float4*)&qks[s * 512 + 256 + (lane << 2)];
            float td = hlo.x * ql.x;
            td = fmaf(hlo.y, ql.y, td); td = fmaf(hlo.z, ql.z, td); td = fmaf(hlo.w, ql.w, td);
            td = fmaf(hhi.x, qh.x, td); td = fmaf(hhi.y, qh.y, td);
            td = fmaf(hhi.z, qh.z, td); td = fmaf(hhi.w, qh.w, td);
            dd[s] = td;
        }
        // fold reduction -> lane holds full logit for slot (lane>>3)&7
        float r4[4];
#pragma unroll
        for (int s = 0; s < 4; ++s) {
            float snd = hb5 ? dd[s] : dd[s + 4];
            float kp  = hb5 ? dd[s + 4] : dd[s];
            r4[s] = kp + __shfl_xor(snd, 32, 64);
        }
        float r2[2];
#pragma unroll
        for (int s = 0; s < 2; ++s) {
            float snd = hb4 ? r4[s] : r4[s + 2];
            float kp  = hb4 ? r4[s + 2] : r4[s];
            r2[s] = kp + __shfl_xor(snd, 16, 64);
        }
        float v;
        {
            float snd = hb3 ? r2[0] : r2[1];
            float kp  = hb3 ? r2[1] : r2[0];
            v = kp + __shfl_xor(snd, 8, 64);
        }
        v += __shfl_xor(v, 4, 64);
        v += __shfl_xor(v, 2, 64);
        v += __shfl_xor(v, 1, 64);
        // softmax across slot groups
        float m = v;
        m = fmaxf(m, __shfl_xor(m, 8, 64));
        m = fmaxf(m, __shfl_xor(m, 16, 64));
        m = fmaxf(m, __shfl_xor(m, 32, 64));
        float pexp = __expf(v - m);
        float ssum = pexp;
        ssum += __shfl_xor(ssum, 8, 64);
        ssum += __shfl_xor(ssum, 16, 64);
        ssum += __shfl_xor(ssum, 32, 64);
        float amine = fmaf(pexp, cnorm / ssum, eadd);
        float av[8];
#pragma unroll
        for (int s = 0; s < 8; ++s) av[s] = __shfl(amine, (s << 3) | gbase, 64);
#pragma unroll
        for (int s = 0; s < 8; ++s) {
            alo[s].x = fmaf(av[s], hlo.x, alo[s].x); alo[s].y = fmaf(av[s], hlo.y, alo[s].y);
            alo[s].z = fmaf(av[s], hlo.z, alo[s].z); alo[s].w = fmaf(av[s], hlo.w, alo[s].w);
            ahi[s].x = fmaf(av[s], hhi.x, ahi[s].x); ahi[s].y = fmaf(av[s], hhi.y, ahi[s].y);
            ahi[s].z = fmaf(av[s], hhi.z, ahi[s].z); ahi[s].w = fmaf(av[s], hhi.w, ahi[s].w);
        }
        x0lo = x1lo; x0hi = x1hi; x1lo = nlo; x1hi = nhi;
    }

    // cross-wave reduce (8 waves) into LDS
    for (int w = 0; w < 8; ++w) {
        if (wid == w) {
#pragma unroll
            for (int s = 0; s < 8; ++s) {
                float* p0 = &u0s[s * 512 + (lane << 2)];
                float* p1 = p0 + 256;
                if (w == 0) {
                    *(float4*)p0 = alo[s];
                    *(float4*)p1 = ahi[s];
                } else {
                    float4 v0 = *(float4*)p0;
                    v0.x += alo[s].x; v0.y += alo[s].y; v0.z += alo[s].z; v0.w += alo[s].w;
                    *(float4*)p0 = v0;
                    float4 v1 = *(float4*)p1;
                    v1.x += ahi[s].x; v1.y += ahi[s].y; v1.z += ahi[s].z; v1.w += ahi[s].w;
                    *(float4*)p1 = v1;
                }
            }
        }
        __syncthreads();
    }
    float4* d4 = (float4*)(p.part + (size_t)beta * 4096);
    const float4* s4 = (const float4*)u0s;
    d4[tid] = s4[tid];
    d4[tid + 512] = s4[tid + 512];
}

// ---------------------------------------------------------------- persistent kernel
__global__ __launch_bounds__(TPB_, 2) void slot_persist(Params p) {
    __shared__ float smem[2 * 64 * 68];    // 34.8 KB, unioned across stages
    cg::grid_group grid = cg::this_grid();
    const int beta = blockIdx.x;
    const int tid  = threadIdx.x;

    // ---- P1: slot init + LN_s (1 row/block), then Mqk / Wiv tiles
    {
        int row = beta, d = tid;
        float v = fmaf(p.sg[(row & 7) * D_ + d], p.noise[(size_t)row * D_ + d],
                       p.mu[(row & 7) * D_ + d]);
        p.slots[(size_t)row * D_ + d] = v;
        float mean, rs;
        row_stats(v, smem, tid, mean, rs);
        p.sn[(size_t)row * D_ + d] = fmaf((v - mean) * rs, p.ln_s_g[d], p.ln_s_b[d]);
    }
    __syncthreads();
    if (beta < 64) {
        // Mqk[d][e] = sum_k wk[k][d] * wq[k][e]   (8x8 tiles)
        int ri = beta >> 3, ci = beta & 7;
        tile_mm<1,1,0,0>(p.wk, p.wq, nullptr, nullptr, p.Mqk, 512, ri*64, ci*64, smem, tid);
    } else {
        // Wiv[g][d] = sum_e w_ih[g][e] * wv[e][d]  (24x8 tiles)
        int t2 = beta - 64, ri = t2 >> 3, ci = t2 & 7;
        tile_mm<0,1,0,0>(p.w_ih, p.wv, nullptr, nullptr, p.Wiv, 512, ri*64, ci*64, smem, tid);
    }
    grid.sync();
    // ---- P2: qk0 = sn @ Mqk^T  (4x8 tiles)
    if (beta < 32) {
        int ri = beta >> 3, ci = beta & 7;
        tile_mm<0,0,0,0>(p.sn, p.Mqk, nullptr, nullptr, p.qk, 512, ri*64, ci*64, smem, tid);
    }
    grid.sync();

    for (int it = 0; it < ITERS_; ++it) {
        // ---- S1: attention pass over inputs
        attn_stage(p, beta, tid, smem);
        grid.sync();
        // ---- S2: gh = slots @ w_hh^T + b_hh (96 tiles)  |  u0 reduce (128 blocks x 2 rows)
        if (beta < 96) {
            int ri = beta / 24, ci = beta % 24;
            tile_mm<0,0,0,0>(p.slots, p.w_hh, p.b_hh, nullptr, p.gh, 1536, ri*64, ci*64, smem, tid);
        } else if (beta < 224) {
            int r0 = (beta - 96) * 2;
            if (tid < 256) {
                int r = r0 + (tid >> 7), q = tid & 127;
                const float4* pp = (const float4*)p.part;
                size_t base = (size_t)(r >> 3) * 8 * 1024 + (size_t)(r & 7) * 128 + q;
                float4 acc = make_float4(0.f, 0.f, 0.f, 0.f);
#pragma unroll
                for (int cc = 0; cc < 8; ++cc) {
                    float4 v = pp[base + (size_t)cc * 1024];
                    acc.x += v.x; acc.y += v.y; acc.z += v.z; acc.w += v.w;
                }
                ((float4*)p.u0)[(size_t)r * 128 + q] = acc;
            }
        }
        grid.sync();
        // ---- S3: gi = u0 @ Wiv^T + b_ih (96 tiles)
        if (beta < 96) {
            int ri = beta / 24, ci = beta % 24;
            tile_mm<0,0,0,0>(p.u0, p.Wiv, p.b_ih, nullptr, p.gi, 1536, ri*64, ci*64, smem, tid);
        }
        grid.sync();
        // ---- S4a: GRU + LN_m (1 row/block)
        {
            int row = beta, d = tid;
            const float* gib = p.gi + (size_t)row * 1536;
            const float* ghb = p.gh + (size_t)row * 1536;
            float gir = gib[d], giz = gib[d + 512], gin = gib[d + 1024];
            float ghr = ghb[d], ghz = ghb[d + 512], ghn = ghb[d + 1024];
            float r = sigmoid_f(gir + ghr);
            float z = sigmoid_f(giz + ghz);
            float nn = tanh_f(fmaf(r, ghn, gin));
            float s2v = fmaf(1.0f - z, nn, z * p.slots[(size_t)row * D_ + d]);
            p.s2b[(size_t)row * D_ + d] = s2v;
            float mean, rs;
            row_stats(s2v, smem, tid, mean, rs);
            p.h0[(size_t)row * D_ + d] = fmaf((s2v - mean) * rs, p.ln_m_g[d], p.ln_m_b[d]);
        }
        grid.sync();
        // ---- S4b: h = relu(h0 @ w1^T + b1) (32 tiles)
        if (beta < 32) {
            int ri = beta >> 3, ci = beta & 7;
            tile_mm<0,0,1,0>(p.h0, p.w1, p.b1, nullptr, p.hb, 512, ri*64, ci*64, smem, tid);
        }
        grid.sync();
        // ---- S5: out = s2 + h @ w2^T + b2 (32 tiles)
        int last = (it == ITERS_ - 1);
        float* dst = last ? p.out : p.slots;
        if (beta < 32) {
            int ri = beta >> 3, ci = beta & 7;
            tile_mm<0,0,0,1>(p.hb, p.w2, p.b2, p.s2b, dst, 512, ri*64, ci*64, smem, tid);
        }
        if (!last) {
            grid.sync();
            // ---- S6a: sn = LN_s(slots) (1 row/block)
            {
                int row = beta, d = tid;
                float v = p.slots[(size_t)row * D_ + d];
                float mean, rs;
                row_stats(v, smem, tid, mean, rs);
                p.sn[(size_t)row * D_ + d] = fmaf((v - mean) * rs, p.ln_s_g[d], p.ln_s_b[d]);
            }
            grid.sync();
            // ---- S6b: qk = sn @ Mqk^T (32 tiles)
            if (beta < 32) {
                int ri = beta >> 3, ci = beta & 7;
                tile_mm<0,0,0,0>(p.sn, p.Mqk, nullptr, nullptr, p.qk, 512, ri*64, ci*64, smem, tid);
            }
            grid.sync();
        }
    }
}

// ---------------------------------------------------------------- launch
extern "C" void kernel_launch(void* const* d_in, const int* in_sizes, int n_in,
                              void* d_out, int out_size, void* d_ws, size_t ws_size,
                              hipStream_t stream) {
    Params prm;
    prm.inputs  = (const float*)d_in[0];
    prm.noise   = (const float*)d_in[1];
    prm.mu      = (const float*)d_in[2];
    prm.sg      = (const float*)d_in[3];
    prm.ln_in_g = (const float*)d_in[4];
    prm.ln_in_b = (const float*)d_in[5];
    prm.ln_s_g  = (const float*)d_in[6];
    prm.ln_s_b  = (const float*)d_in[7];
    prm.wq      = (const float*)d_in[8];
    prm.wk      = (const float*)d_in[9];
    prm.wv      = (const float*)d_in[10];
    prm.w_ih    = (const float*)d_in[11];
    prm.w_hh    = (const float*)d_in[12];
    prm.b_ih    = (const float*)d_in[13];
    prm.b_hh    = (const float*)d_in[14];
    prm.ln_m_g  = (const float*)d_in[15];
    prm.ln_m_b  = (const float*)d_in[16];
    prm.w1      = (const float*)d_in[17];
    prm.b1      = (const float*)d_in[18];
    prm.w2      = (const float*)d_in[19];
    prm.b2      = (const float*)d_in[20];

    float* ws = (float*)d_ws;
    const size_t SLOT = (size_t)B_ * S_ * D_;      // 131072
    size_t o = 0;
    prm.slots = ws + o; o += SLOT;
    prm.sn    = ws + o; o += SLOT;
    prm.qk    = ws + o; o += SLOT;
    prm.u0    = ws + o; o += SLOT;
    prm.s2b   = ws + o; o += SLOT;
    prm.h0    = ws + o; o += SLOT;
    prm.hb    = ws + o; o += SLOT;
    prm.gi    = ws + o; o += 3 * SLOT;
    prm.gh    = ws + o; o += 3 * SLOT;
    prm.Mqk   = ws + o; o += (size_t)D_ * D_;      // 262144
    prm.Wiv   = ws + o; o += (size_t)3 * D_ * D_;  // 786432
    prm.part  = ws + o; o += (size_t)GRID_ * S_ * D_;  // 1048576
    prm.out   = (float*)d_out;

    void* args[] = { &prm };
    hipLaunchCooperativeKernel((const void*)slot_persist, dim3(GRID_), dim3(TPB_),
                               args, 0, stream);
}

// Round 4
// 857.198 us; speedup vs baseline: 1.6757x; 1.6757x over previous
//
#include <hip/hip_runtime.h>

#define B_ 32
#define N_ 4096
#define D_ 512
#define S_ 8
#define ITERS_ 3

__device__ __forceinline__ float sigmoid_f(float x) {
    return 1.0f / (1.0f + __expf(-x));
}
__device__ __forceinline__ float tanh_f(float x) {
    float e = __expf(2.0f * x);
    return 1.0f - 2.0f / (e + 1.0f);
}

// ---------------------------------------------------------------- slot init (+ LN stats per row)
__global__ __launch_bounds__(256) void k_init(const float* __restrict__ noise,
                                              const float* __restrict__ mu,
                                              const float* __restrict__ sg,
                                              float* __restrict__ slots,
                                              float* __restrict__ stats) {
    int wid = threadIdx.x >> 6, lane = threadIdx.x & 63;
    int row = blockIdx.x * 4 + wid;                       // 0..255
    const float4* nz = (const float4*)(noise + (size_t)row * D_);
    const float4* m4 = (const float4*)(mu + (size_t)(row & 7) * D_);
    const float4* s4 = (const float4*)(sg + (size_t)(row & 7) * D_);
    float4 v0 = nz[lane], v1 = nz[64 + lane];
    float4 a0 = m4[lane], a1 = m4[64 + lane];
    float4 c0 = s4[lane], c1 = s4[64 + lane];
    v0.x = fmaf(c0.x, v0.x, a0.x); v0.y = fmaf(c0.y, v0.y, a0.y);
    v0.z = fmaf(c0.z, v0.z, a0.z); v0.w = fmaf(c0.w, v0.w, a0.w);
    v1.x = fmaf(c1.x, v1.x, a1.x); v1.y = fmaf(c1.y, v1.y, a1.y);
    v1.z = fmaf(c1.z, v1.z, a1.z); v1.w = fmaf(c1.w, v1.w, a1.w);
    float4* o4 = (float4*)(slots + (size_t)row * D_);
    o4[lane] = v0; o4[64 + lane] = v1;
    float s1 = v0.x + v0.y + v0.z + v0.w + v1.x + v1.y + v1.z + v1.w;
    float s2 = v0.x*v0.x; s2 = fmaf(v0.y,v0.y,s2); s2 = fmaf(v0.z,v0.z,s2); s2 = fmaf(v0.w,v0.w,s2);
    s2 = fmaf(v1.x,v1.x,s2); s2 = fmaf(v1.y,v1.y,s2); s2 = fmaf(v1.z,v1.z,s2); s2 = fmaf(v1.w,v1.w,s2);
#pragma unroll
    for (int off = 32; off > 0; off >>= 1) {
        s1 += __shfl_xor(s1, off, 64);
        s2 += __shfl_xor(s2, off, 64);
    }
    if (lane == 0) {
        float mean = s1 * (1.0f / D_);
        float var  = s2 * (1.0f / D_) - mean * mean;
        stats[row * 2]     = mean;
        stats[row * 2 + 1] = rsqrtf(var + 1e-5f);
    }
}

// ---------------------------------------------------------------- small GEMM (proven R2)
// WT=0: C = A[M,K] @ W[K,N]; WT=1: C = A[M,K] @ W[N,K]^T; WT=2: C = A[K,M]^T @ W[K,N]
// LNA=1: A read through LayerNorm (stats per row + g/b per k)
template<int WT, int LNA>
__global__ __launch_bounds__(256) void k_gemm(const float* __restrict__ A,
                                              const float* __restrict__ W,
                                              const float* __restrict__ bias,
                                              const float* __restrict__ resid,
                                              float* __restrict__ C,
                                              int M, int N, int K, int relu,
                                              const float* __restrict__ stats,
                                              const float* __restrict__ lng,
                                              const float* __restrict__ lnb) {
    __shared__ float As[64][68];   // [k][m], padded
    __shared__ float Ws[64][36];   // [k][n], padded
    int t  = threadIdx.x;
    int bm = blockIdx.y * 64, bn = blockIdx.x * 32;
    int tm = t >> 4, tn = t & 15;
    float acc[4][2] = {{0.f,0.f},{0.f,0.f},{0.f,0.f},{0.f,0.f}};

    for (int kk = 0; kk < K; kk += 64) {
        __syncthreads();
        if (WT == 2) {
#pragma unroll
            for (int r = 0; r < 4; ++r) {
                int idx = t + r * 256;
                int k = idx >> 4, m4 = idx & 15;
                float4 a4 = *(const float4*)(A + (size_t)(kk + k) * M + bm + (m4 << 2));
                *(float4*)&As[k][m4 << 2] = a4;
            }
        } else {
#pragma unroll
            for (int r = 0; r < 4; ++r) {
                int flat = t * 4 + r * 1024;
                int m = flat >> 6, k = flat & 63;
                float4 a4 = *(const float4*)(A + (size_t)(bm + m) * K + kk + k);
                if (LNA) {
                    float mean = stats[(bm + m) * 2];
                    float rs   = stats[(bm + m) * 2 + 1];
                    float4 g4 = *(const float4*)(lng + kk + k);
                    float4 b4 = *(const float4*)(lnb + kk + k);
                    a4.x = fmaf((a4.x - mean) * rs, g4.x, b4.x);
                    a4.y = fmaf((a4.y - mean) * rs, g4.y, b4.y);
                    a4.z = fmaf((a4.z - mean) * rs, g4.z, b4.z);
                    a4.w = fmaf((a4.w - mean) * rs, g4.w, b4.w);
                }
                As[k + 0][m] = a4.x; As[k + 1][m] = a4.y;
                As[k + 2][m] = a4.z; As[k + 3][m] = a4.w;
            }
        }
        if (WT == 1) {
#pragma unroll
            for (int r = 0; r < 2; ++r) {
                int flat = t * 4 + r * 1024;
                int n = flat >> 6, k = flat & 63;
                float4 w4 = *(const float4*)(W + (size_t)(bn + n) * K + kk + k);
                Ws[k + 0][n] = w4.x; Ws[k + 1][n] = w4.y;
                Ws[k + 2][n] = w4.z; Ws[k + 3][n] = w4.w;
            }
        } else {
#pragma unroll
            for (int r = 0; r < 2; ++r) {
                int flat = t * 4 + r * 1024;
                int k = flat >> 5, n = flat & 31;
                float4 w4 = *(const float4*)(W + (size_t)(kk + k) * N + bn + n);
                *(float4*)&Ws[k][n] = w4;
            }
        }
        __syncthreads();
#pragma unroll
        for (int k = 0; k < 64; ++k) {
            float4 a = *(const float4*)&As[k][tm << 2];
            float2 w = *(const float2*)&Ws[k][tn << 1];
            acc[0][0] = fmaf(a.x, w.x, acc[0][0]); acc[0][1] = fmaf(a.x, w.y, acc[0][1]);
            acc[1][0] = fmaf(a.y, w.x, acc[1][0]); acc[1][1] = fmaf(a.y, w.y, acc[1][1]);
            acc[2][0] = fmaf(a.z, w.x, acc[2][0]); acc[2][1] = fmaf(a.z, w.y, acc[2][1]);
            acc[3][0] = fmaf(a.w, w.x, acc[3][0]); acc[3][1] = fmaf(a.w, w.y, acc[3][1]);
        }
    }
#pragma unroll
    for (int i = 0; i < 4; ++i) {
#pragma unroll
        for (int j = 0; j < 2; ++j) {
            int row = bm + (tm << 2) + i;
            int col = bn + (tn << 1) + j;
            float v = acc[i][j];
            if (bias)  v += bias[col];
            if (relu)  v = fmaxf(v, 0.0f);
            if (resid) v += resid[(size_t)row * N + col];
            C[(size_t)row * N + col] = v;
        }
    }
}

// ---------------------------------------------------------------- q-prep: qt = g.*qk (k-major), C1, C2
__global__ __launch_bounds__(256) void k_qprep(const float* __restrict__ qk,
                                               const float* __restrict__ g,
                                               const float* __restrict__ bvec,
                                               float* __restrict__ qt,
                                               float* __restrict__ c12) {
    __shared__ float qts[4096];
    __shared__ float qks[4096];
    int b = blockIdx.x, t = threadIdx.x;
    const float4* src = (const float4*)(qk + (size_t)b * 4096);
    const float4* g4  = (const float4*)g;
    float4* qtg = (float4*)(qt + (size_t)b * 4096);
#pragma unroll
    for (int r = 0; r < 4; ++r) {
        int f = t + r * 256;                     // f = s*128 + d4
        float4 v  = src[f];
        float4 gg = g4[f & 127];
        float4 qv = make_float4(v.x*gg.x, v.y*gg.y, v.z*gg.z, v.w*gg.w);
        *(float4*)&qts[f * 4] = qv;
        *(float4*)&qks[f * 4] = v;
        // transposed layout: [k4][s] so kA reads 32 contiguous floats per k4
        qtg[(f & 127) * 8 + (f >> 7)] = qv;
    }
    __syncthreads();
    int s = t >> 5, j = t & 31;
    float c1p = 0.f, c2p = 0.f;
#pragma unroll 4
    for (int e = 0; e < 16; ++e) {
        int d = j + 32 * e;
        c1p += qts[s * 512 + d];
        c2p = fmaf(bvec[d], qks[s * 512 + d], c2p);
    }
#pragma unroll
    for (int off = 16; off > 0; off >>= 1) {
        c1p += __shfl_xor(c1p, off, 64);
        c2p += __shfl_xor(c2p, off, 64);
    }
    if (j == 0) { c12[b * 16 + s] = c1p; c12[b * 16 + 8 + s] = c2p; }
}

// ---------------------------------------------------------------- attn pass A: 1 row/thread
// raw-x dots + on-the-fly LN stats -> logits -> softmax -> write w8, a8, (mu,rs)
__global__ __launch_bounds__(256) void k_attnA(const float* __restrict__ x,
                                               const float* __restrict__ qt,
                                               const float* __restrict__ c12,
                                               float* __restrict__ wa,
                                               float* __restrict__ murs) {
    const int b = blockIdx.y;
    const int n = blockIdx.x * 256 + threadIdx.x;
    const size_t gr = (size_t)b * N_ + n;
    const float4* rp = (const float4*)(x + gr * D_);
    const float4* qp = (const float4*)(qt + (size_t)b * 4096);

    float dot[8] = {0.f,0.f,0.f,0.f,0.f,0.f,0.f,0.f};
    float sx = 0.f, sxx = 0.f;
#pragma unroll 4
    for (int k4 = 0; k4 < 128; ++k4) {
        float4 xv = rp[k4];
        sx += xv.x + xv.y + xv.z + xv.w;
        sxx = fmaf(xv.x, xv.x, sxx); sxx = fmaf(xv.y, xv.y, sxx);
        sxx = fmaf(xv.z, xv.z, sxx); sxx = fmaf(xv.w, xv.w, sxx);
#pragma unroll
        for (int s = 0; s < 8; ++s) {
            float4 qv = qp[k4 * 8 + s];          // wave-uniform -> s_load
            dot[s] = fmaf(xv.x, qv.x, dot[s]);
            dot[s] = fmaf(xv.y, qv.y, dot[s]);
            dot[s] = fmaf(xv.z, qv.z, dot[s]);
            dot[s] = fmaf(xv.w, qv.w, dot[s]);
        }
    }
    float mean = sx * (1.0f / D_);
    float rs   = rsqrtf(sxx * (1.0f / D_) - mean * mean + 1e-5f);
    float mc   = -rs * mean;
    float l[8];
#pragma unroll
    for (int s = 0; s < 8; ++s)
        l[s] = fmaf(rs, dot[s], fmaf(mc, c12[b * 16 + s], c12[b * 16 + 8 + s]));
    float mx = l[0];
#pragma unroll
    for (int s = 1; s < 8; ++s) mx = fmaxf(mx, l[s]);
    float p[8], psum = 0.f;
#pragma unroll
    for (int s = 0; s < 8; ++s) { p[s] = __expf(l[s] - mx); psum += p[s]; }
    const float cnorm = 1.0f / (1.0f + 8.0f * 1e-8f);
    const float eadd  = 1e-8f * cnorm;
    float ip = cnorm / psum;
    float a[8], w[8];
#pragma unroll
    for (int s = 0; s < 8; ++s) { a[s] = fmaf(p[s], ip, eadd); w[s] = a[s] * rs; }
    float4* wo = (float4*)(wa + gr * 16);
    wo[0] = make_float4(w[0], w[1], w[2], w[3]);
    wo[1] = make_float4(w[4], w[5], w[6], w[7]);
    wo[2] = make_float4(a[0], a[1], a[2], a[3]);
    wo[3] = make_float4(a[4], a[5], a[6], a[7]);
    ((float2*)murs)[gr] = make_float2(mean, rs);
}

// ---------------------------------------------------------------- attn pass B: P[s][d] partials
__global__ __launch_bounds__(256) void k_attnB(const float* __restrict__ x,
                                               const float* __restrict__ wa,
                                               float* __restrict__ part) {
    const int b = blockIdx.y, nc = blockIdx.x, t = threadIdx.x;
    const int d0 = t * 2;
    const float*  xp = x  + ((size_t)b * N_ + (size_t)nc * 256) * D_ + d0;
    const float4* wp = (const float4*)(wa + ((size_t)b * N_ + (size_t)nc * 256) * 16);
    float P[8][2];
#pragma unroll
    for (int s = 0; s < 8; ++s) { P[s][0] = 0.f; P[s][1] = 0.f; }
#pragma unroll 4
    for (int i = 0; i < 256; ++i) {
        float2 xv = *(const float2*)(xp + (size_t)i * D_);
        float4 w01 = wp[i * 4];                   // wave-uniform -> s_load
        float4 w23 = wp[i * 4 + 1];
        P[0][0] = fmaf(w01.x, xv.x, P[0][0]); P[0][1] = fmaf(w01.x, xv.y, P[0][1]);
        P[1][0] = fmaf(w01.y, xv.x, P[1][0]); P[1][1] = fmaf(w01.y, xv.y, P[1][1]);
        P[2][0] = fmaf(w01.z, xv.x, P[2][0]); P[2][1] = fmaf(w01.z, xv.y, P[2][1]);
        P[3][0] = fmaf(w01.w, xv.x, P[3][0]); P[3][1] = fmaf(w01.w, xv.y, P[3][1]);
        P[4][0] = fmaf(w23.x, xv.x, P[4][0]); P[4][1] = fmaf(w23.x, xv.y, P[4][1]);
        P[5][0] = fmaf(w23.y, xv.x, P[5][0]); P[5][1] = fmaf(w23.y, xv.y, P[5][1]);
        P[6][0] = fmaf(w23.z, xv.x, P[6][0]); P[6][1] = fmaf(w23.z, xv.y, P[6][1]);
        P[7][0] = fmaf(w23.w, xv.x, P[7][0]); P[7][1] = fmaf(w23.w, xv.y, P[7][1]);
    }
    float* o = part + (size_t)(b * 16 + nc) * 4096;
#pragma unroll
    for (int s = 0; s < 8; ++s)
        *(float2*)(o + s * 512 + d0) = make_float2(P[s][0], P[s][1]);
}

// ---------------------------------------------------------------- u0 reduce + affine correction
__global__ __launch_bounds__(256) void k_ured(const float* __restrict__ part,
                                              const float* __restrict__ wa,
                                              const float* __restrict__ murs,
                                              const float* __restrict__ g,
                                              const float* __restrict__ bvec,
                                              float* __restrict__ u0) {
    __shared__ float red[256][16];
    const int b = blockIdx.x, t = threadIdx.x;
    float aA[8] = {0,0,0,0,0,0,0,0}, aT[8] = {0,0,0,0,0,0,0,0};
    const float4* wp = (const float4*)(wa + (size_t)b * N_ * 16);
    const float2* mp = ((const float2*)murs) + (size_t)b * N_;
    for (int i = t; i < N_; i += 256) {
        float4 w01 = wp[i * 4], w23 = wp[i * 4 + 1];
        float4 a01 = wp[i * 4 + 2], a23 = wp[i * 4 + 3];
        float mu = mp[i].x;
        aA[0] += a01.x; aA[1] += a01.y; aA[2] += a01.z; aA[3] += a01.w;
        aA[4] += a23.x; aA[5] += a23.y; aA[6] += a23.z; aA[7] += a23.w;
        aT[0] = fmaf(w01.x, mu, aT[0]); aT[1] = fmaf(w01.y, mu, aT[1]);
        aT[2] = fmaf(w01.z, mu, aT[2]); aT[3] = fmaf(w01.w, mu, aT[3]);
        aT[4] = fmaf(w23.x, mu, aT[4]); aT[5] = fmaf(w23.y, mu, aT[5]);
        aT[6] = fmaf(w23.z, mu, aT[6]); aT[7] = fmaf(w23.w, mu, aT[7]);
    }
#pragma unroll
    for (int q = 0; q < 8; ++q) { red[t][q] = aA[q]; red[t][8 + q] = aT[q]; }
    __syncthreads();
    for (int step = 128; step > 0; step >>= 1) {
        if (t < step) {
#pragma unroll
            for (int q = 0; q < 16; ++q) red[t][q] += red[t + step][q];
        }
        __syncthreads();
    }
    float Av[8], Tv[8];
#pragma unroll
    for (int q = 0; q < 8; ++q) { Av[q] = red[0][q]; Tv[q] = red[0][8 + q]; }
    const int d0 = t * 2;
    float gg0 = g[d0], gg1 = g[d0 + 1], bb0 = bvec[d0], bb1 = bvec[d0 + 1];
#pragma unroll
    for (int s = 0; s < 8; ++s) {
        float p0 = 0.f, p1 = 0.f;
#pragma unroll
        for (int nc = 0; nc < 16; ++nc) {
            float2 pv = *(const float2*)(part + (size_t)(b * 16 + nc) * 4096 + s * 512 + d0);
            p0 += pv.x; p1 += pv.y;
        }
        float* o = u0 + (size_t)(b * 8 + s) * D_ + d0;
        o[0] = fmaf(gg0, p0 - Tv[s], Av[s] * bb0);
        o[1] = fmaf(gg1, p1 - Tv[s], Av[s] * bb1);
    }
}

// ---------------------------------------------------------------- P2: GRU + MLP + LN + qk_next (proven R2)
__global__ __launch_bounds__(512) void k_p2(const float* __restrict__ gi,
                                            const float* __restrict__ gh,
                                            const float* __restrict__ slots,
                                            const float* __restrict__ w1, const float* __restrict__ b1,
                                            const float* __restrict__ w2, const float* __restrict__ b2,
                                            const float* __restrict__ wqkT,
                                            const float* __restrict__ ln_m_g, const float* __restrict__ ln_m_b,
                                            const float* __restrict__ ln_s_g, const float* __restrict__ ln_s_b,
                                            float* __restrict__ dst, float* __restrict__ qkout, int last) {
    __shared__ float s2s[2][512];
    __shared__ float t0s[2][512];
    __shared__ float hs[2][512];
    __shared__ float stat[4];
    const int t = threadIdx.x;
    const int wid = t >> 6, lane = t & 63;
    const int r0 = blockIdx.x * 2;

#pragma unroll
    for (int j = 0; j < 2; ++j) {
        int flat = t + j * 512;
        int r = flat >> 9, d = flat & 511;
        size_t row = r0 + r;
        const float* gib = gi + row * 1536;
        const float* ghb = gh + row * 1536;
        float gir = gib[d], giz = gib[d + 512], gin = gib[d + 1024];
        float ghr = ghb[d], ghz = ghb[d + 512], ghn = ghb[d + 1024];
        float rr = sigmoid_f(gir + ghr);
        float zz = sigmoid_f(giz + ghz);
        float nn = tanh_f(fmaf(rr, ghn, gin));
        float sp = slots[row * 512 + d];
        s2s[r][d] = fmaf(1.0f - zz, nn, zz * sp);
    }
    __syncthreads();
    if (wid < 2) {
        const float4* sr = (const float4*)s2s[wid];
        float4 a = sr[lane], bq = sr[64 + lane];
        float s1 = a.x + a.y + a.z + a.w + bq.x + bq.y + bq.z + bq.w;
        float s2 = a.x*a.x; s2 = fmaf(a.y,a.y,s2); s2 = fmaf(a.z,a.z,s2); s2 = fmaf(a.w,a.w,s2);
        s2 = fmaf(bq.x,bq.x,s2); s2 = fmaf(bq.y,bq.y,s2); s2 = fmaf(bq.z,bq.z,s2); s2 = fmaf(bq.w,bq.w,s2);
#pragma unroll
        for (int off = 32; off > 0; off >>= 1) {
            s1 += __shfl_xor(s1, off, 64);
            s2 += __shfl_xor(s2, off, 64);
        }
        if (lane == 0) {
            float mean = s1 * (1.0f / D_);
            float var  = s2 * (1.0f / D_) - mean * mean;
            stat[wid * 2] = mean;
            stat[wid * 2 + 1] = rsqrtf(var + 1e-5f);
        }
    }
    __syncthreads();
#pragma unroll
    for (int j = 0; j < 2; ++j) {
        int flat = t + j * 512;
        int r = flat >> 9, d = flat & 511;
        t0s[r][d] = fmaf((s2s[r][d] - stat[r * 2]) * stat[r * 2 + 1], ln_m_g[d], ln_m_b[d]);
    }
    __syncthreads();
    {
        const int c = t;
        const float4* wr = (const float4*)(w1 + (size_t)c * 512);
        float a0 = 0.f, a1 = 0.f;
#pragma unroll 8
        for (int k4 = 0; k4 < 128; ++k4) {
            float4 w4 = wr[k4];
            float4 q0 = *(const float4*)&t0s[0][k4 << 2];
            float4 q1 = *(const float4*)&t0s[1][k4 << 2];
            a0 = fmaf(q0.x, w4.x, a0); a0 = fmaf(q0.y, w4.y, a0);
            a0 = fmaf(q0.z, w4.z, a0); a0 = fmaf(q0.w, w4.w, a0);
            a1 = fmaf(q1.x, w4.x, a1); a1 = fmaf(q1.y, w4.y, a1);
            a1 = fmaf(q1.z, w4.z, a1); a1 = fmaf(q1.w, w4.w, a1);
        }
        float bc = b1[c];
        hs[0][c] = fmaxf(a0 + bc, 0.f);
        hs[1][c] = fmaxf(a1 + bc, 0.f);
    }
    __syncthreads();
    {
        const int c = t;
        const float4* wr = (const float4*)(w2 + (size_t)c * 512);
        float a0 = 0.f, a1 = 0.f;
#pragma unroll 8
        for (int k4 = 0; k4 < 128; ++k4) {
            float4 w4 = wr[k4];
            float4 q0 = *(const float4*)&hs[0][k4 << 2];
            float4 q1 = *(const float4*)&hs[1][k4 << 2];
            a0 = fmaf(q0.x, w4.x, a0); a0 = fmaf(q0.y, w4.y, a0);
            a0 = fmaf(q0.z, w4.z, a0); a0 = fmaf(q0.w, w4.w, a0);
            a1 = fmaf(q1.x, w4.x, a1); a1 = fmaf(q1.y, w4.y, a1);
            a1 = fmaf(q1.z, w4.z, a1); a1 = fmaf(q1.w, w4.w, a1);
        }
        float bc = b2[c];
        float o0 = s2s[0][c] + a0 + bc;
        float o1 = s2s[1][c] + a1 + bc;
        dst[(size_t)r0 * 512 + c] = o0;
        dst[(size_t)(r0 + 1) * 512 + c] = o1;
        s2s[0][c] = o0;
        s2s[1][c] = o1;
    }
    if (last) return;
    __syncthreads();
    if (wid < 2) {
        const float4* sr = (const float4*)s2s[wid];
        float4 a = sr[lane], bq = sr[64 + lane];
        float s1 = a.x + a.y + a.z + a.w + bq.x + bq.y + bq.z + bq.w;
        float s2 = a.x*a.x; s2 = fmaf(a.y,a.y,s2); s2 = fmaf(a.z,a.z,s2); s2 = fmaf(a.w,a.w,s2);
        s2 = fmaf(bq.x,bq.x,s2); s2 = fmaf(bq.y,bq.y,s2); s2 = fmaf(bq.z,bq.z,s2); s2 = fmaf(bq.w,bq.w,s2);
#pragma unroll
        for (int off = 32; off > 0; off >>= 1) {
            s1 += __shfl_xor(s1, off, 64);
            s2 += __shfl_xor(s2, off, 64);
        }
        if (lane == 0) {
            float mean = s1 * (1.0f / D_);
            float var  = s2 * (1.0f / D_) - mean * mean;
            stat[wid * 2] = mean;
            stat[wid * 2 + 1] = rsqrtf(var + 1e-5f);
        }
    }
    __syncthreads();
#pragma unroll
    for (int j = 0; j < 2; ++j) {
        int flat = t + j * 512;
        int r = flat >> 9, d = flat & 511;
        t0s[r][d] = fmaf((s2s[r][d] - stat[r * 2]) * stat[r * 2 + 1], ln_s_g[d], ln_s_b[d]);
    }
    __syncthreads();
    {
        const int c = t;
        const float4* wr = (const float4*)(wqkT + (size_t)c * 512);
        float a0 = 0.f, a1 = 0.f;
#pragma unroll 8
        for (int k4 = 0; k4 < 128; ++k4) {
            float4 w4 = wr[k4];
            float4 q0 = *(const float4*)&t0s[0][k4 << 2];
            float4 q1 = *(const float4*)&t0s[1][k4 << 2];
            a0 = fmaf(q0.x, w4.x, a0); a0 = fmaf(q0.y, w4.y, a0);
            a0 = fmaf(q0.z, w4.z, a0); a0 = fmaf(q0.w, w4.w, a0);
            a1 = fmaf(q1.x, w4.x, a1); a1 = fmaf(q1.y, w4.y, a1);
            a1 = fmaf(q1.z, w4.z, a1); a1 = fmaf(q1.w, w4.w, a1);
        }
        qkout[(size_t)r0 * 512 + c] = a0;
        qkout[(size_t)(r0 + 1) * 512 + c] = a1;
    }
}

// ---------------------------------------------------------------- launch
extern "C" void kernel_launch(void* const* d_in, const int* in_sizes, int n_in,
                              void* d_out, int out_size, void* d_ws, size_t ws_size,
                              hipStream_t stream) {
    const float* inputs  = (const float*)d_in[0];
    const float* noise   = (const float*)d_in[1];
    const float* mu      = (const float*)d_in[2];
    const float* sg      = (const float*)d_in[3];
    const float* ln_in_g = (const float*)d_in[4];
    const float* ln_in_b = (const float*)d_in[5];
    const float* ln_s_g  = (const float*)d_in[6];
    const float* ln_s_b  = (const float*)d_in[7];
    const float* wq      = (const float*)d_in[8];
    const float* wk      = (const float*)d_in[9];
    const float* wv      = (const float*)d_in[10];
    const float* w_ih    = (const float*)d_in[11];
    const float* w_hh    = (const float*)d_in[12];
    const float* b_ih    = (const float*)d_in[13];
    const float* b_hh    = (const float*)d_in[14];
    const float* ln_m_g  = (const float*)d_in[15];
    const float* ln_m_b  = (const float*)d_in[16];
    const float* w1      = (const float*)d_in[17];
    const float* b1      = (const float*)d_in[18];
    const float* w2      = (const float*)d_in[19];
    const float* b2      = (const float*)d_in[20];

    float* ws = (float*)d_ws;
    const size_t SLOT = (size_t)B_ * S_ * D_;      // 131072
    size_t o = 0;
    float* slots = ws + o; o += SLOT;
    float* qk    = ws + o; o += SLOT;
    float* u0    = ws + o; o += SLOT;
    float* gi    = ws + o; o += 3 * SLOT;
    float* gh    = ws + o; o += 3 * SLOT;
    float* Mqk   = ws + o; o += (size_t)D_ * D_;          // 262144
    float* Wiv   = ws + o; o += (size_t)3 * D_ * D_;      // 786432
    float* statsS= ws + o; o += 512;
    float* qt    = ws + o; o += SLOT;                     // q-tilde, k-major
    float* c12   = ws + o; o += 512;
    float* murs  = ws + o; o += (size_t)2 * B_ * N_;      // 262144
    float* wa    = ws + o; o += (size_t)16 * B_ * N_;     // 2097152
    float* part  = ws + o; o += (size_t)16 * B_ * 4096;   // 2097152

    // ---- prologue
    // Mqk[d][f] = sum_e wk[e][d] * wq[e][f]
    k_gemm<2,0><<<dim3(16, 8), 256, 0, stream>>>(wk, wq, nullptr, nullptr, Mqk,
                                                 512, 512, 512, 0, nullptr, nullptr, nullptr);
    // Wiv[g][d] = sum_e w_ih[g][e] * wv[e][d]
    k_gemm<0,0><<<dim3(16, 24), 256, 0, stream>>>(w_ih, wv, nullptr, nullptr, Wiv,
                                                  1536, 512, 512, 0, nullptr, nullptr, nullptr);
    k_init<<<64, 256, 0, stream>>>(noise, mu, sg, slots, statsS);
    // qk0 = LN_s(slots) @ Mqk^T
    k_gemm<1,1><<<dim3(16, 4), 256, 0, stream>>>(slots, Mqk, nullptr, nullptr, qk,
                                                 256, 512, 512, 0, statsS, ln_s_g, ln_s_b);

    for (int it = 0; it < ITERS_; ++it) {
        k_qprep<<<B_, 256, 0, stream>>>(qk, ln_in_g, ln_in_b, qt, c12);
        k_attnA<<<dim3(16, B_), 256, 0, stream>>>(inputs, qt, c12, wa, murs);
        k_attnB<<<dim3(16, B_), 256, 0, stream>>>(inputs, wa, part);
        k_ured<<<B_, 256, 0, stream>>>(part, wa, murs, ln_in_g, ln_in_b, u0);
        // gh = slots @ w_hh^T + b_hh
        k_gemm<1,0><<<dim3(48, 4), 256, 0, stream>>>(slots, w_hh, b_hh, nullptr, gh,
                                                     256, 1536, 512, 0, nullptr, nullptr, nullptr);
        // gi = u0 @ Wiv^T + b_ih
        k_gemm<1,0><<<dim3(48, 4), 256, 0, stream>>>(u0, Wiv, b_ih, nullptr, gi,
                                                     256, 1536, 512, 0, nullptr, nullptr, nullptr);
        int last = (it == ITERS_ - 1);
        float* dst = last ? (float*)d_out : slots;
        k_p2<<<128, 512, 0, stream>>>(gi, gh, slots, w1, b1, w2, b2, Mqk,
                                      ln_m_g, ln_m_b, ln_s_g, ln_s_b, dst, qk, last);
    }
}